// Round 13
// baseline (517.719 us; speedup 1.0000x reference)
//
#include <hip/hip_runtime.h>

#define Nn 32
#define Cc 64
#define Vv 25
#define Tt 1024

typedef __attribute__((ext_vector_type(4))) float f32x4;
typedef __attribute__((ext_vector_type(8))) short bf16x8;
typedef __attribute__((ext_vector_type(4))) unsigned short u16x4;

__device__ __forceinline__ unsigned short f2bf(float f) {
    union { float f; unsigned u; } a; a.f = f;
    unsigned u = a.u;
    u += 0x7fff + ((u >> 16) & 1);   // RNE
    return (unsigned short)(u >> 16);
}

// ---------------- fast path ----------------

// BOTH operand workspaces in MFMA-FRAGMENT ORDER.
// xb (R9): chunk idx (((n*Vv+w)*4+sl)*2048) + wv*512 + kc*256 + ni*64 + lane
//   holds x[c'=(kc*4+quad)*8+kk][w][t=sl*256+wv*64+ni*16+m].
// Weff (R13): chunk idx (v*Vv+w)*512 + (kc*4+mi)*64 + lane
//   holds Weff[c=mi*16+m][cp=kc*32+quad*8+kk]  (lane = quad*16+m).
// -> ALL gc loads are base + lane*16B, fully coalesced; gc needs NO LDS.
__global__ __launch_bounds__(256) void prep_fused(
        const float* __restrict__ x, const float* __restrict__ W,
        const float* __restrict__ A, unsigned short* __restrict__ xb,
        unsigned short* __restrict__ Weff) {
    int bid = blockIdx.x;
    if (bid < Vv * Vv) {
        // ---- Weff part: fragment-ordered output ----
        int v = bid / Vv;
        int w = bid - v * Vv;
        float a0 = A[(0 * Vv + w) * Vv + v];
        float a1 = A[(1 * Vv + w) * Vv + v];
        float a2 = A[(2 * Vv + w) * Vv + v];
        const float* Wb = W + (size_t)w * 192 * 64;
        unsigned short* o = Weff + (size_t)(v * Vv + w) * 4096;
        int tid = threadIdx.x;
        int mi = tid >> 6;
        int lane = tid & 63;
        int m = lane & 15, quad = lane >> 4;
        int c = mi * 16 + m;
        const float* r0 = Wb + (size_t)(c * 3 + 0) * 64;
        const float* r1 = Wb + (size_t)(c * 3 + 1) * 64;
        const float* r2 = Wb + (size_t)(c * 3 + 2) * 64;
        #pragma unroll
        for (int kc = 0; kc < 2; ++kc) {
            bf16x8 ov;
            #pragma unroll
            for (int kk = 0; kk < 8; ++kk) {
                int cp = kc * 32 + quad * 8 + kk;
                float val = a0 * r0[cp] + a1 * r1[cp] + a2 * r2[cp];
                ov[kk] = (short)f2bf(val);
            }
            *(bf16x8*)&o[((kc * 4 + mi) * 64 + lane) * 8] = ov;
        }
        return;
    }
    // ---- x-convert: one (n, w, sl) tile (R9, unchanged) ----
    int pid = bid - Vv * Vv;
    int n = pid / (Vv * 4);
    int rem = pid - n * (Vv * 4);
    int w = rem >> 2;
    int sl = rem & 3;

    int tid = threadIdx.x;
    int wq = tid >> 6;            // = gc's wv
    int l  = tid & 63;
    int quad = l >> 4, m = l & 15;

    const float* xw = x + ((size_t)n * Cc * Vv + w) * Tt + sl * 256 + wq * 64 + m;
    unsigned short* dst = xb +
        ((((size_t)(n * Vv + w) * 4 + sl) * 2048) + (size_t)wq * 512 + l) * 8;

    #pragma unroll
    for (int kc = 0; kc < 2; ++kc) {
        float vals[4][8];
        #pragma unroll
        for (int kk = 0; kk < 8; ++kk) {
            int cp = (kc * 4 + quad) * 8 + kk;
            const float* row = xw + (size_t)cp * (Vv * Tt);
            #pragma unroll
            for (int ni = 0; ni < 4; ++ni)
                vals[ni][kk] = __builtin_nontemporal_load(row + ni * 16);
        }
        #pragma unroll
        for (int ni = 0; ni < 4; ++ni) {
            bf16x8 o;
            #pragma unroll
            for (int kk = 0; kk < 8; ++kk) o[kk] = (short)f2bf(vals[ni][kk]);
            *(bf16x8*)&dst[(size_t)(kc * 256 + ni * 64) * 8] = o;
        }
    }
}

// out[n, 0:64, v, t0:t0+256] = sum_w Weff[v,w] @ xb[n,w,t0:t0+256,:]
// R13: NO LDS, NO BARRIER. Both A and B fragment-ordered -> all loads
// coalesced global->reg. Waves free-run (8/CU anti-phase overlap replaces
// the R3-R12 lockstep whose post-barrier LDS burst capped MfmaUtil ~41%).
// Skeleton = R10's proven issue-before-wait + counted vmcnt:
//   step w: issue A(w+1) [ping-pong, 8 ld], B(w+2) [ring-3, 8 ld];
//           vmcnt(24) drains exactly B(w)+A(w); COMP(w) pure-register.
// Queue at wait: B(w),A(w) | B(w+1),A(w+1),B(w+2) = 40 -> keep 24.
// Prologue: B(0); A(0),B(1) -> 24 outstanding. w=23: issue A(24) only,
// vmcnt(16). w=24: vmcnt(0).
// Registers: B 3x32 (96, proven live in R10) + A 2x32 (64) + addr ~ 176
// arch + 64 AGPR = 240 unified -> fits 2 waves/SIMD. HEALTH: VGPR ~108
// => regalloc collapsed (R7 mode) => revert; WRITE spike => spill => revert.
__global__ __launch_bounds__(256, 2) void gc_fast(
        const unsigned short* __restrict__ xb,
        const unsigned short* __restrict__ Weff,
        float* __restrict__ out) {
    int bid = blockIdx.x;                 // 3200 = 8 xcd * (16 slices * 25 v), v fastest
    int xcd = bid & 7;
    int lid = bid >> 3;
    int v = lid % Vv;
    int s = lid / Vv;                     // 0..15
    int slice = (xcd << 4) + s;           // 0..127
    int n  = slice >> 2;
    int sl = slice & 3;
    int t0 = sl << 8;

    int tid = threadIdx.x;
    int lane = tid & 63, wv = tid >> 6;
    int m = lane & 15, quad = lane >> 4;

    const unsigned short* wg = Weff + (size_t)v * (Vv * 4096) + (size_t)lane * 8;
    const unsigned short* xbase = xb + ((size_t)(n * Vv * 4 + sl)) * 2048 * 8;

    int boff[8];
    #pragma unroll
    for (int q = 0; q < 8; ++q) boff[q] = ((wv * 8 + q) * 64 + lane) * 8;

    f32x4 acc[4][4];
    #pragma unroll
    for (int i = 0; i < 4; ++i)
        #pragma unroll
        for (int j = 0; j < 4; ++j)
            acc[i][j] = (f32x4){0.f, 0.f, 0.f, 0.f};

    bf16x8 b0v[8], b1v[8], b2v[8];
    bf16x8 afA[8], afB[8];

#define SB __builtin_amdgcn_sched_barrier(0)
#define VMCNT(N_) asm volatile("s_waitcnt vmcnt(" #N_ ")" ::: "memory")

#define ISSUE_AF(AF, w_) do { \
    const unsigned short* aw_ = wg + (size_t)(w_) * 4096; \
    _Pragma("unroll") \
    for (int j_ = 0; j_ < 8; ++j_) \
        AF[j_] = *(const bf16x8*)(aw_ + (size_t)j_ * 512); \
} while (0)

#define ISSUE_B(BN, w_) do { \
    const unsigned short* xw_ = xbase + (size_t)(w_) * 65536; \
    _Pragma("unroll") \
    for (int q_ = 0; q_ < 8; ++q_) \
        BN[q_] = *(const bf16x8*)(xw_ + boff[q_]); \
} while (0)

#define COMP(AF, BC) do { \
    __builtin_amdgcn_s_setprio(1); \
    _Pragma("unroll") \
    for (int mi_ = 0; mi_ < 4; ++mi_) \
        _Pragma("unroll") \
        for (int ni_ = 0; ni_ < 4; ++ni_) \
            acc[mi_][ni_] = __builtin_amdgcn_mfma_f32_16x16x32_bf16( \
                AF[mi_], BC[ni_], acc[mi_][ni_], 0, 0, 0); \
    _Pragma("unroll") \
    for (int mi_ = 0; mi_ < 4; ++mi_) \
        _Pragma("unroll") \
        for (int ni_ = 0; ni_ < 4; ++ni_) \
            acc[mi_][ni_] = __builtin_amdgcn_mfma_f32_16x16x32_bf16( \
                AF[mi_ + 4], BC[ni_ + 4], acc[mi_][ni_], 0, 0, 0); \
    __builtin_amdgcn_s_setprio(0); \
} while (0)

// Step w: issue A(w+1) (into AFn, consumed at COMP(w-1) already), then
// B(w+2) (ring-3 buf freed at COMP(w-1)); drain B(w)+A(w); COMP(w).
#define STEP(AFc, AFn, BC, BN, w_) do { \
    ISSUE_AF(AFn, (w_) + 1); \
    ISSUE_B(BN, (w_) + 2); \
    SB; VMCNT(24); SB; \
    COMP(AFc, BC); \
    SB; \
} while (0)

    // prologue ("step -2": B(0); "step -1": A(0),B(1)) -> 24 outstanding
    ISSUE_B(b0v, 0);
    ISSUE_AF(afA, 0);
    ISSUE_B(b1v, 1);
    SB;

    //   AFc  AFn  BC   BN   w     (AF = af{w%2}; BC = b{w%3}; BN = b{(w+2)%3})
    STEP(afA, afB, b0v, b2v,  0);
    STEP(afB, afA, b1v, b0v,  1);
    STEP(afA, afB, b2v, b1v,  2);
    STEP(afB, afA, b0v, b2v,  3);
    STEP(afA, afB, b1v, b0v,  4);
    STEP(afB, afA, b2v, b1v,  5);
    STEP(afA, afB, b0v, b2v,  6);
    STEP(afB, afA, b1v, b0v,  7);
    STEP(afA, afB, b2v, b1v,  8);
    STEP(afB, afA, b0v, b2v,  9);
    STEP(afA, afB, b1v, b0v, 10);
    STEP(afB, afA, b2v, b1v, 11);
    STEP(afA, afB, b0v, b2v, 12);
    STEP(afB, afA, b1v, b0v, 13);
    STEP(afA, afB, b2v, b1v, 14);
    STEP(afB, afA, b0v, b2v, 15);
    STEP(afA, afB, b1v, b0v, 16);
    STEP(afB, afA, b2v, b1v, 17);
    STEP(afA, afB, b0v, b2v, 18);
    STEP(afB, afA, b1v, b0v, 19);
    STEP(afA, afB, b2v, b1v, 20);
    STEP(afB, afA, b0v, b2v, 21);
    STEP(afA, afB, b1v, b0v, 22);
    // w=23: issue A(24) only (into afA, freed at COMP(22)).
    // Queue: B(23),A(23),B(24),A(24) = 32 -> vmcnt(16) drains B(23)+A(23).
    ISSUE_AF(afA, 24);
    SB; VMCNT(16); SB;
    COMP(afB, b2v);
    SB;
    // w=24: drain everything.
    VMCNT(0);
    SB;
    COMP(afA, b0v);

#undef STEP
#undef COMP
#undef ISSUE_B
#undef ISSUE_AF
#undef VMCNT
#undef SB

    // epilogue: D layout col(t)=lane&15, row(c)=quad*4+reg  (verified in R1)
    // NT stores (R10 best; R12 proved plain stores slightly worse).
    float* og = out + ((size_t)n * Cc * Vv + v) * Tt + t0 + wv * 64 + m;
    #pragma unroll
    for (int mi = 0; mi < 4; ++mi)
        #pragma unroll
        for (int r = 0; r < 4; ++r) {
            int c = mi * 16 + quad * 4 + r;
            float* orow = og + (size_t)c * Vv * Tt;
            #pragma unroll
            for (int ni = 0; ni < 4; ++ni)
                __builtin_nontemporal_store(acc[mi][ni][r], &orow[ni * 16]);
        }
}

// ---------------- fallback path (R1, proven) ----------------

__global__ __launch_bounds__(256) void weff_prep_plain(
        const float* __restrict__ W, const float* __restrict__ A,
        unsigned short* __restrict__ Weff) {
    int v = blockIdx.x / Vv;
    int w = blockIdx.x - v * Vv;
    float a0 = A[(0 * Vv + w) * Vv + v];
    float a1 = A[(1 * Vv + w) * Vv + v];
    float a2 = A[(2 * Vv + w) * Vv + v];
    const float* Wb = W + (size_t)w * 192 * 64;
    unsigned short* o = Weff + (size_t)(v * Vv + w) * 4096;
    int e0 = threadIdx.x * 16;
    #pragma unroll
    for (int i = 0; i < 16; ++i) {
        int e = e0 + i;
        int c = e >> 6, cp = e & 63;
        float val = a0 * Wb[(c * 3 + 0) * 64 + cp]
                  + a1 * Wb[(c * 3 + 1) * 64 + cp]
                  + a2 * Wb[(c * 3 + 2) * 64 + cp];
        o[e] = f2bf(val);
    }
}

__global__ __launch_bounds__(256, 2) void gc_plain(
        const float* __restrict__ x, const unsigned short* __restrict__ Weff,
        float* __restrict__ out) {
    __shared__ __align__(16) unsigned short xs[256 * 72];
    __shared__ __align__(16) unsigned short wa[64 * 72];
    int bid = blockIdx.x;
    int xcd = bid & 7;
    int lid = bid >> 3;
    int v, s;
    if (lid < 13 * 16) { v = lid % 13;            s = lid / 13; }
    else { int l2 = lid - 13 * 16; v = 13 + l2 % 12; s = l2 / 12; }
    int slice = (xcd << 4) + s;
    int n  = slice >> 2;
    int t0 = (slice & 3) << 8;
    int tid  = threadIdx.x;
    int lane = tid & 63;
    int wv   = tid >> 6;
    int m    = lane & 15;
    int quad = lane >> 4;
    int cc = tid & 7;
    int tt = tid >> 3;
    f32x4 acc[4][4];
    #pragma unroll
    for (int i = 0; i < 4; ++i)
        #pragma unroll
        for (int j = 0; j < 4; ++j)
            acc[i][j] = (f32x4){0.f, 0.f, 0.f, 0.f};
    const float* xg = x + (size_t)n * Cc * Vv * Tt + t0 + tt * 4;
    const bf16x8* wg = (const bf16x8*)(Weff + (size_t)v * Vv * 4096);
    for (int w = 0; w < Vv; ++w) {
        if (w) __syncthreads();
        #pragma unroll
        for (int r = 0; r < 2; ++r) {
            int q = r * 256 + tid;
            int c = q >> 3, b = q & 7;
            *(bf16x8*)&wa[c * 72 + b * 8] = wg[w * 512 + q];
        }
        {
            bf16x8 rows[8];
            #pragma unroll
            for (int i = 0; i < 8; ++i) {
                int cp = cc * 8 + i;
                const float* p = xg + ((size_t)cp * Vv + w) * Tt;
                float4 f0 = *(const float4*)p;
                float4 f1 = *(const float4*)(p + 128);
                rows[0][i] = (short)f2bf(f0.x); rows[1][i] = (short)f2bf(f0.y);
                rows[2][i] = (short)f2bf(f0.z); rows[3][i] = (short)f2bf(f0.w);
                rows[4][i] = (short)f2bf(f1.x); rows[5][i] = (short)f2bf(f1.y);
                rows[6][i] = (short)f2bf(f1.z); rows[7][i] = (short)f2bf(f1.w);
            }
            #pragma unroll
            for (int j = 0; j < 4; ++j) {
                *(bf16x8*)&xs[(tt * 4 + j) * 72 + cc * 8]       = rows[j];
                *(bf16x8*)&xs[(128 + tt * 4 + j) * 72 + cc * 8] = rows[4 + j];
            }
        }
        __syncthreads();
        #pragma unroll
        for (int kc = 0; kc < 2; ++kc) {
            int ko = kc * 32 + quad * 8;
            bf16x8 afr[4], bfr[4];
            #pragma unroll
            for (int mi = 0; mi < 4; ++mi)
                afr[mi] = *(const bf16x8*)&wa[(mi * 16 + m) * 72 + ko];
            #pragma unroll
            for (int ni = 0; ni < 4; ++ni)
                bfr[ni] = *(const bf16x8*)&xs[(wv * 64 + ni * 16 + m) * 72 + ko];
            #pragma unroll
            for (int mi = 0; mi < 4; ++mi)
                #pragma unroll
                for (int ni = 0; ni < 4; ++ni)
                    acc[mi][ni] = __builtin_amdgcn_mfma_f32_16x16x32_bf16(
                        afr[mi], bfr[ni], acc[mi][ni], 0, 0, 0);
        }
    }
    float* og = out + ((size_t)n * Cc * Vv + v) * Tt + t0 + wv * 64 + m;
    #pragma unroll
    for (int mi = 0; mi < 4; ++mi)
        #pragma unroll
        for (int r = 0; r < 4; ++r) {
            int c = mi * 16 + quad * 4 + r;
            float* orow = og + (size_t)c * Vv * Tt;
            #pragma unroll
            for (int ni = 0; ni < 4; ++ni)
                orow[ni * 16] = acc[mi][ni][r];
        }
}

extern "C" void kernel_launch(void* const* d_in, const int* in_sizes, int n_in,
                              void* d_out, int out_size, void* d_ws, size_t ws_size,
                              hipStream_t stream) {
    const float* x = (const float*)d_in[0];   // [32,64,25,1024]
    const float* W = (const float*)d_in[1];   // [25,192,64]
    const float* A = (const float*)d_in[2];   // [3,25,25]
    float* out = (float*)d_out;

    const size_t xb_elems   = (size_t)Nn * Vv * Tt * 64;       // 52,428,800
    const size_t weff_elems = (size_t)Vv * Vv * 4096;          //  2,560,000
    const size_t need = (xb_elems + weff_elems) * sizeof(unsigned short);

    if (ws_size >= need) {
        unsigned short* xb   = (unsigned short*)d_ws;
        unsigned short* Weff = xb + xb_elems;
        prep_fused<<<dim3(Vv * Vv + Nn * Vv * 4), dim3(256), 0, stream>>>(x, W, A, xb, Weff);
        gc_fast<<<dim3(3200), dim3(256), 0, stream>>>(xb, Weff, out);
    } else {
        unsigned short* Weff = (unsigned short*)d_ws;
        weff_prep_plain<<<dim3(Vv * Vv), dim3(256), 0, stream>>>(W, A, Weff);
        gc_plain<<<dim3(3200), dim3(256), 0, stream>>>(x, Weff, out);
    }
}

// Round 14
// 494.220 us; speedup vs baseline: 1.0475x; 1.0475x over previous
//
#include <hip/hip_runtime.h>

#define Nn 32
#define Cc 64
#define Vv 25
#define Tt 1024

typedef __attribute__((ext_vector_type(4))) float f32x4;
typedef __attribute__((ext_vector_type(8))) short bf16x8;
typedef __attribute__((ext_vector_type(4))) unsigned short u16x4;

__device__ __forceinline__ unsigned short f2bf(float f) {
    union { float f; unsigned u; } a; a.f = f;
    unsigned u = a.u;
    u += 0x7fff + ((u >> 16) & 1);   // RNE
    return (unsigned short)(u >> 16);
}

__device__ __forceinline__ void gl_lds16(const unsigned short* g, unsigned short* l) {
    __builtin_amdgcn_global_load_lds(
        (const __attribute__((address_space(1))) unsigned int*)g,
        (__attribute__((address_space(3))) unsigned int*)l, 16, 0, 0);
}

// ---------------- fast path ----------------

// xb in MFMA-FRAGMENT ORDER (R9): chunk (16B) index
//   (((n*Vv + w)*4 + sl)*2048) + wv*512 + kc*256 + ni*64 + lane
// -> gc's B loads are base + lane*16B, fully coalesced.
// Weff: XOR-swizzled [c][chunk] tiles for the gc LDS path (R3 layout).
// Fused prep: blocks [0,625) build Weff; blocks [625,3825) convert one
// (n,w,sl) 256t x 64c' tile.
__global__ __launch_bounds__(256) void prep_fused(
        const float* __restrict__ x, const float* __restrict__ W,
        const float* __restrict__ A, unsigned short* __restrict__ xb,
        unsigned short* __restrict__ Weff) {
    int bid = blockIdx.x;
    if (bid < Vv * Vv) {
        // ---- Weff part ----
        int v = bid / Vv;
        int w = bid - v * Vv;
        float a0 = A[(0 * Vv + w) * Vv + v];
        float a1 = A[(1 * Vv + w) * Vv + v];
        float a2 = A[(2 * Vv + w) * Vv + v];
        const float* Wb = W + (size_t)w * 192 * 64;
        unsigned short* o = Weff + (size_t)(v * Vv + w) * 4096;
        int c  = threadIdx.x >> 2;
        int c0 = (threadIdx.x & 3) * 16;
        #pragma unroll
        for (int i = 0; i < 16; ++i) {
            int cp = c0 + i;
            float val = a0 * Wb[(c * 3 + 0) * 64 + cp]
                      + a1 * Wb[(c * 3 + 1) * 64 + cp]
                      + a2 * Wb[(c * 3 + 2) * 64 + cp];
            int jl = cp >> 3;
            o[c * 64 + ((jl ^ (c & 7)) << 3) + (cp & 7)] = f2bf(val);
        }
        return;
    }
    // ---- x-convert: one (n, w, sl) tile ----
    int pid = bid - Vv * Vv;
    int n = pid / (Vv * 4);
    int rem = pid - n * (Vv * 4);
    int w = rem >> 2;
    int sl = rem & 3;

    int tid = threadIdx.x;
    int wq = tid >> 6;            // = gc's wv
    int l  = tid & 63;
    int quad = l >> 4, m = l & 15;

    const float* xw = x + ((size_t)n * Cc * Vv + w) * Tt + sl * 256 + wq * 64 + m;
    unsigned short* dst = xb +
        ((((size_t)(n * Vv + w) * 4 + sl) * 2048) + (size_t)wq * 512 + l) * 8;

    #pragma unroll
    for (int kc = 0; kc < 2; ++kc) {
        float vals[4][8];
        #pragma unroll
        for (int kk = 0; kk < 8; ++kk) {
            int cp = (kc * 4 + quad) * 8 + kk;
            const float* row = xw + (size_t)cp * (Vv * Tt);
            #pragma unroll
            for (int ni = 0; ni < 4; ++ni)
                vals[ni][kk] = __builtin_nontemporal_load(row + ni * 16);
        }
        #pragma unroll
        for (int ni = 0; ni < 4; ++ni) {
            bf16x8 o;
            #pragma unroll
            for (int kk = 0; kk < 8; ++kk) o[kk] = (short)f2bf(vals[ni][kk]);
            *(bf16x8*)&dst[(size_t)(kc * 256 + ni * 64) * 8] = o;
        }
    }
}

// out[n, 0:64, v, t0:t0+256] = sum_w Weff[v,w] @ xb[n,w,t0:t0+256,:]
// R14 = R10 RESTORED (best measured: gc 180us, total 490us).
// Session conclusions baked into this structure:
//  - Lockstep barrier is a CONVOY: barrier-synced waves keep same-w loads
//    temporally phased in L2. Barrier-free variants (R7, R13) are SLOWER
//    (de-phased L2 access + A redundancy), not regalloc-collapsed.
//  - A via global_load_lds RING-4 (32KB); B ring-3 reg bufs, fragment-
//    ordered xb -> fully coalesced (R9, +10us).
//  - af-preload: A fragments for step w+1 ds_read during step w, so COMP
//    is pure-register after the barrier (R10, +10us).
//  - NT epilogue stores (R12 proved plain stores slightly worse).
//  - 2 waves/SIMD is register-pinned (172/256 unified); M=128/wave needs
//    ~313 -> infeasible. MfmaUtil ~41% / HBM 37% / L2 ~50%: latency+convoy
//    structural plateau for this decomposition.
// Ledger: at step w outstanding pre-wait = B(w)8 + A(w+1)2,B(w+1)8 +
// A(w+2)2,B(w+2)8 = 28 -> vmcnt(18) drains exactly B(w)+A(w+1).
// Prologue vmcnt(16); w=23 vmcnt(8); w=24 vmcnt(0), no barrier.
__global__ __launch_bounds__(256, 2) void gc_fast(
        const unsigned short* __restrict__ xb,
        const unsigned short* __restrict__ Weff,
        float* __restrict__ out) {
    __shared__ __align__(16) unsigned short wa[4][4096];   // 32 KB ring-4

    int bid = blockIdx.x;                 // 3200 = 8 xcd * (16 slices * 25 v), v fastest
    int xcd = bid & 7;
    int lid = bid >> 3;
    int v = lid % Vv;
    int s = lid / Vv;                     // 0..15
    int slice = (xcd << 4) + s;           // 0..127
    int n  = slice >> 2;
    int sl = slice & 3;
    int t0 = sl << 8;

    int tid = threadIdx.x;
    int lane = tid & 63, wv = tid >> 6;
    int m = lane & 15, quad = lane >> 4;

    const unsigned short* wg = Weff + (size_t)v * (Vv * 4096);
    const unsigned short* xbase = xb + ((size_t)(n * Vv * 4 + sl)) * 2048 * 8;

    int coff0 = ((quad)     ^ (m & 7)) << 3;   // A kc=0 chunk offset (swizzled)
    int coff1 = ((4 + quad) ^ (m & 7)) << 3;   // A kc=1
    int arow[4];
    #pragma unroll
    for (int mi = 0; mi < 4; ++mi) arow[mi] = (mi * 16 + m) * 64;
    int boff[8];
    #pragma unroll
    for (int q = 0; q < 8; ++q) boff[q] = ((wv * 8 + q) * 64 + lane) * 8;

    f32x4 acc[4][4];
    #pragma unroll
    for (int i = 0; i < 4; ++i)
        #pragma unroll
        for (int j = 0; j < 4; ++j)
            acc[i][j] = (f32x4){0.f, 0.f, 0.f, 0.f};

    bf16x8 b0v[8], b1v[8], b2v[8];
    bf16x8 afA[8], afB[8];

#define SB __builtin_amdgcn_sched_barrier(0)
#define VMCNT(N_) asm volatile("s_waitcnt vmcnt(" #N_ ")" ::: "memory")

#define ISSUE_A(WBUF, w_) do { \
    const unsigned short* s_ = wg + (size_t)(w_) * 4096 + tid * 8; \
    gl_lds16(s_,        &wa[WBUF][tid * 8]); \
    gl_lds16(s_ + 2048, &wa[WBUF][2048 + tid * 8]); \
} while (0)

#define ISSUE_B(BN, w_) do { \
    const unsigned short* xw_ = xbase + (size_t)(w_) * 65536; \
    _Pragma("unroll") \
    for (int q_ = 0; q_ < 8; ++q_) \
        BN[q_] = *(const bf16x8*)(xw_ + boff[q_]); \
} while (0)

#define LDREAD(AF, RBUF) do { \
    const unsigned short* cur_ = &wa[RBUF][0]; \
    _Pragma("unroll") \
    for (int mi_ = 0; mi_ < 4; ++mi_) { \
        AF[mi_]     = *(const bf16x8*)(cur_ + arow[mi_] + coff0); \
        AF[mi_ + 4] = *(const bf16x8*)(cur_ + arow[mi_] + coff1); \
    } \
} while (0)

#define COMP(AF, BC) do { \
    __builtin_amdgcn_s_setprio(1); \
    _Pragma("unroll") \
    for (int mi_ = 0; mi_ < 4; ++mi_) \
        _Pragma("unroll") \
        for (int ni_ = 0; ni_ < 4; ++ni_) \
            acc[mi_][ni_] = __builtin_amdgcn_mfma_f32_16x16x32_bf16( \
                AF[mi_], BC[ni_], acc[mi_][ni_], 0, 0, 0); \
    _Pragma("unroll") \
    for (int mi_ = 0; mi_ < 4; ++mi_) \
        _Pragma("unroll") \
        for (int ni_ = 0; ni_ < 4; ++ni_) \
            acc[mi_][ni_] = __builtin_amdgcn_mfma_f32_16x16x32_bf16( \
                AF[mi_ + 4], BC[ni_ + 4], acc[mi_][ni_], 0, 0, 0); \
    __builtin_amdgcn_s_setprio(0); \
} while (0)

// Step w: issue A(w+2) then B(w+2); vmcnt(18); barrier; COMP(w) pure-reg;
// ds_read af(w+1) from buf RB=(w+1)%4 (overlaps next barrier wait).
#define STEP(AFc, AFn, WB, RB, BC, BN, w_) do { \
    ISSUE_A(WB, (w_) + 2); \
    ISSUE_B(BN, (w_) + 2); \
    SB; VMCNT(18); SB; \
    __builtin_amdgcn_s_barrier(); \
    SB; \
    COMP(AFc, BC); \
    LDREAD(AFn, RB); \
    SB; \
} while (0)

    // prologue: A(0)->buf0, A(1)->buf1 (4 vm, oldest), B(0)->b0, B(1)->b1 (16 vm)
    ISSUE_A(0, 0);
    ISSUE_A(1, 1);
    ISSUE_B(b0v, 0);
    ISSUE_B(b1v, 1);
    SB; VMCNT(16); SB;          // drains A(0),A(1); keeps B(0),B(1)
    __builtin_amdgcn_s_barrier();
    SB;
    LDREAD(afA, 0);             // af(0)
    SB;

    //   AFc  AFn  WB RB  BC   BN   w
    STEP(afA, afB, 2, 1, b0v, b2v,  0);
    STEP(afB, afA, 3, 2, b1v, b0v,  1);
    STEP(afA, afB, 0, 3, b2v, b1v,  2);
    STEP(afB, afA, 1, 0, b0v, b2v,  3);
    STEP(afA, afB, 2, 1, b1v, b0v,  4);
    STEP(afB, afA, 3, 2, b2v, b1v,  5);
    STEP(afA, afB, 0, 3, b0v, b2v,  6);
    STEP(afB, afA, 1, 0, b1v, b0v,  7);
    STEP(afA, afB, 2, 1, b2v, b1v,  8);
    STEP(afB, afA, 3, 2, b0v, b2v,  9);
    STEP(afA, afB, 0, 3, b1v, b0v, 10);
    STEP(afB, afA, 1, 0, b2v, b1v, 11);
    STEP(afA, afB, 2, 1, b0v, b2v, 12);
    STEP(afB, afA, 3, 2, b1v, b0v, 13);
    STEP(afA, afB, 0, 3, b2v, b1v, 14);
    STEP(afB, afA, 1, 0, b0v, b2v, 15);
    STEP(afA, afB, 2, 1, b1v, b0v, 16);
    STEP(afB, afA, 3, 2, b2v, b1v, 17);
    STEP(afA, afB, 0, 3, b0v, b2v, 18);
    STEP(afB, afA, 1, 0, b1v, b0v, 19);
    STEP(afA, afB, 2, 1, b2v, b1v, 20);
    STEP(afB, afA, 3, 2, b0v, b2v, 21);
    STEP(afA, afB, 0, 3, b1v, b0v, 22);
    // w=23 (no issues): outstanding = B(23)8 [w21] + A(24)2,B(24)8 [w22].
    // vmcnt(8) drains B(23) (COMP) + A(24) (LDREAD); keeps B(24).
    SB; VMCNT(8); SB;
    __builtin_amdgcn_s_barrier();
    SB;
    COMP(afB, b2v);
    LDREAD(afA, 0);             // af(24); A(24) in LDS (vmcnt(8)+barrier)
    SB;
    // w=24: drain B(24); no barrier needed (no LDS writer remains).
    VMCNT(0);
    SB;
    COMP(afA, b0v);

#undef STEP
#undef COMP
#undef LDREAD
#undef ISSUE_B
#undef ISSUE_A
#undef VMCNT
#undef SB

    // epilogue: D layout col(t)=lane&15, row(c)=quad*4+reg  (verified in R1)
    // NT stores (R10 best; R12 proved plain stores slightly worse).
    float* og = out + ((size_t)n * Cc * Vv + v) * Tt + t0 + wv * 64 + m;
    #pragma unroll
    for (int mi = 0; mi < 4; ++mi)
        #pragma unroll
        for (int r = 0; r < 4; ++r) {
            int c = mi * 16 + quad * 4 + r;
            float* orow = og + (size_t)c * Vv * Tt;
            #pragma unroll
            for (int ni = 0; ni < 4; ++ni)
                __builtin_nontemporal_store(acc[mi][ni][r], &orow[ni * 16]);
        }
}

// ---------------- fallback path (R1, proven) ----------------

__global__ __launch_bounds__(256) void weff_prep_plain(
        const float* __restrict__ W, const float* __restrict__ A,
        unsigned short* __restrict__ Weff) {
    int v = blockIdx.x / Vv;
    int w = blockIdx.x - v * Vv;
    float a0 = A[(0 * Vv + w) * Vv + v];
    float a1 = A[(1 * Vv + w) * Vv + v];
    float a2 = A[(2 * Vv + w) * Vv + v];
    const float* Wb = W + (size_t)w * 192 * 64;
    unsigned short* o = Weff + (size_t)(v * Vv + w) * 4096;
    int e0 = threadIdx.x * 16;
    #pragma unroll
    for (int i = 0; i < 16; ++i) {
        int e = e0 + i;
        int c = e >> 6, cp = e & 63;
        float val = a0 * Wb[(c * 3 + 0) * 64 + cp]
                  + a1 * Wb[(c * 3 + 1) * 64 + cp]
                  + a2 * Wb[(c * 3 + 2) * 64 + cp];
        o[e] = f2bf(val);
    }
}

__global__ __launch_bounds__(256, 2) void gc_plain(
        const float* __restrict__ x, const unsigned short* __restrict__ Weff,
        float* __restrict__ out) {
    __shared__ __align__(16) unsigned short xs[256 * 72];
    __shared__ __align__(16) unsigned short wa[64 * 72];
    int bid = blockIdx.x;
    int xcd = bid & 7;
    int lid = bid >> 3;
    int v, s;
    if (lid < 13 * 16) { v = lid % 13;            s = lid / 13; }
    else { int l2 = lid - 13 * 16; v = 13 + l2 % 12; s = l2 / 12; }
    int slice = (xcd << 4) + s;
    int n  = slice >> 2;
    int t0 = (slice & 3) << 8;
    int tid  = threadIdx.x;
    int lane = tid & 63;
    int wv   = tid >> 6;
    int m    = lane & 15;
    int quad = lane >> 4;
    int cc = tid & 7;
    int tt = tid >> 3;
    f32x4 acc[4][4];
    #pragma unroll
    for (int i = 0; i < 4; ++i)
        #pragma unroll
        for (int j = 0; j < 4; ++j)
            acc[i][j] = (f32x4){0.f, 0.f, 0.f, 0.f};
    const float* xg = x + (size_t)n * Cc * Vv * Tt + t0 + tt * 4;
    const bf16x8* wg = (const bf16x8*)(Weff + (size_t)v * Vv * 4096);
    for (int w = 0; w < Vv; ++w) {
        if (w) __syncthreads();
        #pragma unroll
        for (int r = 0; r < 2; ++r) {
            int q = r * 256 + tid;
            int c = q >> 3, b = q & 7;
            *(bf16x8*)&wa[c * 72 + b * 8] = wg[w * 512 + q];
        }
        {
            bf16x8 rows[8];
            #pragma unroll
            for (int i = 0; i < 8; ++i) {
                int cp = cc * 8 + i;
                const float* p = xg + ((size_t)cp * Vv + w) * Tt;
                float4 f0 = *(const float4*)p;
                float4 f1 = *(const float4*)(p + 128);
                rows[0][i] = (short)f2bf(f0.x); rows[1][i] = (short)f2bf(f0.y);
                rows[2][i] = (short)f2bf(f0.z); rows[3][i] = (short)f2bf(f0.w);
                rows[4][i] = (short)f2bf(f1.x); rows[5][i] = (short)f2bf(f1.y);
                rows[6][i] = (short)f2bf(f1.z); rows[7][i] = (short)f2bf(f1.w);
            }
            #pragma unroll
            for (int j = 0; j < 4; ++j) {
                *(bf16x8*)&xs[(tt * 4 + j) * 72 + cc * 8]       = rows[j];
                *(bf16x8*)&xs[(128 + tt * 4 + j) * 72 + cc * 8] = rows[4 + j];
            }
        }
        __syncthreads();
        #pragma unroll
        for (int kc = 0; kc < 2; ++kc) {
            int ko = kc * 32 + quad * 8;
            bf16x8 afr[4], bfr[4];
            #pragma unroll
            for (int mi = 0; mi < 4; ++mi)
                afr[mi] = *(const bf16x8*)&wa[(mi * 16 + m) * 72 + ko];
            #pragma unroll
            for (int ni = 0; ni < 4; ++ni)
                bfr[ni] = *(const bf16x8*)&xs[(wv * 64 + ni * 16 + m) * 72 + ko];
            #pragma unroll
            for (int mi = 0; mi < 4; ++mi)
                #pragma unroll
                for (int ni = 0; ni < 4; ++ni)
                    acc[mi][ni] = __builtin_amdgcn_mfma_f32_16x16x32_bf16(
                        afr[mi], bfr[ni], acc[mi][ni], 0, 0, 0);
        }
    }
    float* og = out + ((size_t)n * Cc * Vv + v) * Tt + t0 + wv * 64 + m;
    #pragma unroll
    for (int mi = 0; mi < 4; ++mi)
        #pragma unroll
        for (int r = 0; r < 4; ++r) {
            int c = mi * 16 + quad * 4 + r;
            float* orow = og + (size_t)c * Vv * Tt;
            #pragma unroll
            for (int ni = 0; ni < 4; ++ni)
                orow[ni * 16] = acc[mi][ni][r];
        }
}

extern "C" void kernel_launch(void* const* d_in, const int* in_sizes, int n_in,
                              void* d_out, int out_size, void* d_ws, size_t ws_size,
                              hipStream_t stream) {
    const float* x = (const float*)d_in[0];   // [32,64,25,1024]
    const float* W = (const float*)d_in[1];   // [25,192,64]
    const float* A = (const float*)d_in[2];   // [3,25,25]
    float* out = (float*)d_out;

    const size_t xb_elems   = (size_t)Nn * Vv * Tt * 64;       // 52,428,800
    const size_t weff_elems = (size_t)Vv * Vv * 4096;          //  2,560,000
    const size_t need = (xb_elems + weff_elems) * sizeof(unsigned short);

    if (ws_size >= need) {
        unsigned short* xb   = (unsigned short*)d_ws;
        unsigned short* Weff = xb + xb_elems;
        prep_fused<<<dim3(Vv * Vv + Nn * Vv * 4), dim3(256), 0, stream>>>(x, W, A, xb, Weff);
        gc_fast<<<dim3(3200), dim3(256), 0, stream>>>(xb, Weff, out);
    } else {
        unsigned short* Weff = (unsigned short*)d_ws;
        weff_prep_plain<<<dim3(Vv * Vv), dim3(256), 0, stream>>>(W, A, Weff);
        gc_plain<<<dim3(3200), dim3(256), 0, stream>>>(x, Weff, out);
    }
}